// Round 6
// baseline (78.425 us; speedup 1.0000x reference)
//
#include <hip/hip_runtime.h>
#include <hip/hip_bf16.h>

typedef __bf16 bf16x8 __attribute__((ext_vector_type(8)));
typedef __bf16 bf16x4 __attribute__((ext_vector_type(4)));
typedef float  f32x4  __attribute__((ext_vector_type(4)));

#define LRELU_ALPHA 0.2f
#define LOG2E 1.44269504088896340736f

__device__ __forceinline__ float fexp2(float x) { return exp2f(x); }

// raw barrier: drains LDS (lgkmcnt) but leaves global prefetches (vmcnt) in flight
__device__ __forceinline__ void wg_barrier() {
    asm volatile("s_waitcnt lgkmcnt(0)" ::: "memory");
    __builtin_amdgcn_s_barrier();
    asm volatile("" ::: "memory");
}

// ---------------------------------------------------------------------------
// Kernel 1: h = inp @ W (8 rows/block) -> hb (bf16), f1 = log2e*(h·a1),
// f2 = log2e*(h·a2). h kept ONLY as bf16 (residual tolerance allows it).
// ---------------------------------------------------------------------------
__global__ __launch_bounds__(128) void gat_prep(
    const float* __restrict__ inp, const float* __restrict__ W,
    const float* __restrict__ a,
    __bf16* __restrict__ hb, float* __restrict__ f1, float* __restrict__ f2)
{
    const int r0 = blockIdx.x << 3;
    const int d  = threadIdx.x;
    __shared__ float sIn[8][128];
    __shared__ float sRed[8][4];
    #pragma unroll
    for (int r = 0; r < 8; ++r)
        sIn[r][d] = inp[(size_t)(r0 + r) * 128 + d];
    __syncthreads();

    float acc[8] = {0.f,0.f,0.f,0.f,0.f,0.f,0.f,0.f};
    #pragma unroll 4
    for (int k = 0; k < 128; ++k) {
        float wv = W[k * 128 + d];
        #pragma unroll
        for (int r = 0; r < 8; ++r) acc[r] += sIn[r][k] * wv;
    }

    const float a1 = a[d], a2 = a[128 + d];
    const int wv = d >> 6;
    #pragma unroll
    for (int r = 0; r < 8; ++r) {
        hb[(size_t)(r0 + r) * 128 + d] = (__bf16)acc[r];
        float t1 = acc[r] * a1;
        float t2 = acc[r] * a2;
        #pragma unroll
        for (int m = 1; m < 64; m <<= 1) {
            t1 += __shfl_xor(t1, m);
            t2 += __shfl_xor(t2, m);
        }
        if ((d & 63) == 0) { sRed[r][wv] = t1; sRed[r][2 + wv] = t2; }
    }
    __syncthreads();
    if (d < 8) {
        f1[r0 + d] = (sRed[d][0] + sRed[d][1]) * LOG2E;
        f2[r0 + d] = (sRed[d][2] + sRed[d][3]) * LOG2E;
    }
}

// ---------------------------------------------------------------------------
// Kernel 2: per-batch max of (prescaled) f1
// ---------------------------------------------------------------------------
__global__ __launch_bounds__(256) void gat_f1max(
    const float* __restrict__ f1, float* __restrict__ f1max)
{
    const int b = blockIdx.x;
    const int t = threadIdx.x;
    float m = -1e30f;
    for (int j = t; j < 2048; j += 256) m = fmaxf(m, f1[b * 2048 + j]);
    #pragma unroll
    for (int k = 1; k < 64; k <<= 1) m = fmaxf(m, __shfl_xor(m, k));
    __shared__ float sm[4];
    if ((t & 63) == 0) sm[t >> 6] = m;
    __syncthreads();
    if (t == 0) f1max[b] = fmaxf(fmaxf(sm[0], sm[1]), fmaxf(sm[2], sm[3]));
}

// ---------------------------------------------------------------------------
// Kernel 3: hb (bf16 [b][n][128]) -> pack: fragment-major bf16 B-operands.
// pack element offset = (b*32 + jt)*8192 + frag*512 + lane*8, frag = D*2+jh.
// Fragment lane(il,kg) elem e = h[jt*64 + jh*32 + kg*8 + e][D*16 + il].
// ---------------------------------------------------------------------------
__global__ __launch_bounds__(256) void gat_pack(
    const __bf16* __restrict__ hb, __bf16* __restrict__ pack)
{
    __shared__ __bf16 tile[64][72];
    const int tid = threadIdx.x;
    const int bidx = blockIdx.x;         // 512 blocks
    const int b  = bidx >> 6;
    const int tI = bidx & 63;
    const int n0 = (tI >> 1) << 6;       // j-range 64
    const int d0 = (tI & 1) << 6;        // d-range 64
    #pragma unroll
    for (int pass = 0; pass < 2; ++pass) {
        int row = (tid >> 3) + (pass << 5);     // j within tile
        int c   = (tid & 7) << 3;               // d within tile
        *(bf16x8*)&tile[row][c] =
            *(const bf16x8*)(hb + (size_t)(b * 2048 + n0 + row) * 128 + d0 + c);
    }
    __syncthreads();
    const int lane = tid & 63;
    const int il = lane & 15;
    const int kg = lane >> 4;
    #pragma unroll
    for (int pass = 0; pass < 2; ++pass) {
        const int f  = (tid >> 6) + (pass << 2);   // fragment 0..7 of this block
        const int Dl = f >> 1;
        const int jh = f & 1;
        union { __bf16 e[8]; bf16x8 v; } u;
        #pragma unroll
        for (int e = 0; e < 8; ++e)
            u.e[e] = tile[(jh << 5) + (kg << 3) + e][(Dl << 4) + il];
        const size_t off = (((size_t)(b << 5) + (n0 >> 6)) << 13)
                         + ((size_t)((((d0 >> 4) + Dl) << 1) | jh) << 9)
                         + (lane << 3);
        *(bf16x8*)(pack + off) = u.v;
    }
}

// ---------------------------------------------------------------------------
// Kernel 3b: adj (int32, 128 MB) -> tb bitmask (4 MB), consumer-major:
// tb[row][pj4] = int4 (128 bits); bit (t*4+e) = adj[row][t*64 + pj4*4 + e].
// Pure streaming read (coalesced int4 + ballot) -> should run at ~fill rate.
// ---------------------------------------------------------------------------
__global__ __launch_bounds__(256) void gat_adjpack(
    const int* __restrict__ adj, unsigned int* __restrict__ tb)
{
    __shared__ unsigned long long blt[16][8][4];
    const int tid  = threadIdx.x;
    const int w    = tid >> 6;
    const int lane = tid & 63;
    const int base = blockIdx.x << 4;          // 1024 blocks * 16 rows

    // phase 1: each wave packs 4 rows via ballots
    #pragma unroll
    for (int rr = 0; rr < 4; ++rr) {
        const int rloc = (w << 2) + rr;
        const int* ap = adj + ((size_t)(base + rloc) << 11) + (lane << 2);
        unsigned long long kept = 0ull;
        #pragma unroll
        for (int s = 0; s < 8; ++s) {
            int4 v = *(const int4*)(ap + (s << 8));
            unsigned long long b0 = __ballot(v.x > 0);
            unsigned long long b1 = __ballot(v.y > 0);
            unsigned long long b2 = __ballot(v.z > 0);
            unsigned long long b3 = __ballot(v.w > 0);
            const int e4 = lane & 3;
            unsigned long long be = (e4 == 0) ? b0 : (e4 == 1) ? b1
                                  : (e4 == 2) ? b2 : b3;
            kept = ((lane >> 2) == s) ? be : kept;
        }
        if (lane < 32) blt[rloc][lane >> 2][lane & 3] = kept;
    }
    __syncthreads();

    // phase 2: thread (r, pj4) assembles its consumer int4
    const int r   = tid >> 4;
    const int pj4 = tid & 15;
    unsigned int w0 = 0, w1 = 0, w2 = 0, w3 = 0;
    #pragma unroll
    for (int s = 0; s < 8; ++s) {
        unsigned long long q0 = blt[r][s][0];
        unsigned long long q1 = blt[r][s][1];
        unsigned long long q2 = blt[r][s][2];
        unsigned long long q3 = blt[r][s][3];
        #pragma unroll
        for (int tt = 0; tt < 4; ++tt) {
            const int t = (s << 2) + tt;
            const int L = (tt << 4) + pj4;
            unsigned int nib = (unsigned int)((q0 >> L) & 1)
                             | ((unsigned int)((q1 >> L) & 1) << 1)
                             | ((unsigned int)((q2 >> L) & 1) << 2)
                             | ((unsigned int)((q3 >> L) & 1) << 3);
            const unsigned int sh = (unsigned int)((t & 7) << 2);
            if (t < 8)       w0 |= nib << sh;
            else if (t < 16) w1 |= nib << sh;
            else if (t < 24) w2 |= nib << sh;
            else             w3 |= nib << sh;
        }
    }
    uint4 o; o.x = w0; o.y = w1; o.z = w2; o.w = w3;
    *(uint4*)(tb + (((size_t)(base + r) << 4) + pj4) * 4) = o;
}

// ---------------------------------------------------------------------------
// Kernel 4 v6: fused attention. 512 thr (8 waves = 8 unique d-slices of 16),
// 32 i x 128 d per block. adj from per-thread 128-bit mask (zero global adj
// in loop). B-fragments straight from global pack (L2-resident, unique per
// wave). P double-buffered in LDS; ONE lgkm-barrier per iteration.
// ---------------------------------------------------------------------------
#define PCOMPUTE(TT, BUF) do {                                                \
    float4 fv = *(const float4*)&f1s[((TT) << 6) + (pj4 << 2)];               \
    const unsigned int wv = ((TT) & 16) ? (((TT) & 8) ? aw.w : aw.z)          \
                                        : (((TT) & 8) ? aw.y : aw.x);         \
    const unsigned int nib = wv >> (((TT) & 7) << 2);                         \
    float p0, p1, p2, p3;                                                     \
    { float x = f2v + fv.x; float e1 = fmaxf(x, LRELU_ALPHA * x) - Mshift;    \
      p0 = fexp2(__builtin_fmaf(e1, (float)(nib & 1), -1000.f)); }            \
    { float x = f2v + fv.y; float e1 = fmaxf(x, LRELU_ALPHA * x) - Mshift;    \
      p1 = fexp2(__builtin_fmaf(e1, (float)((nib >> 1) & 1), -1000.f)); }     \
    { float x = f2v + fv.z; float e1 = fmaxf(x, LRELU_ALPHA * x) - Mshift;    \
      p2 = fexp2(__builtin_fmaf(e1, (float)((nib >> 2) & 1), -1000.f)); }     \
    { float x = f2v + fv.w; float e1 = fmaxf(x, LRELU_ALPHA * x) - Mshift;    \
      p3 = fexp2(__builtin_fmaf(e1, (float)((nib >> 3) & 1), -1000.f)); }     \
    bf16x4 pb;                                                                \
    pb[0] = (__bf16)p0; pb[1] = (__bf16)p1;                                   \
    pb[2] = (__bf16)p2; pb[3] = (__bf16)p3;                                   \
    den += (float)pb[0] + (float)pb[1] + (float)pb[2] + (float)pb[3];         \
    *(bf16x4*)(&Ps[BUF][pwo]) = pb;                                           \
} while (0)

__global__ __launch_bounds__(512, 4) void gat_attn6(
    const unsigned int* __restrict__ tb, const __bf16* __restrict__ hb,
    const __bf16* __restrict__ pack, const float* __restrict__ f1g,
    const float* __restrict__ f2g, const float* __restrict__ f1maxg,
    float* __restrict__ out)
{
    const int bid = ((blockIdx.x & 7) << 6) | (blockIdx.x >> 3);  // batch<->XCD
    const int b  = bid >> 6;
    const int i0 = (bid & 63) << 5;
    const int tid = threadIdx.x;

    __shared__ float f1s[2048];
    __shared__ alignas(16) __bf16 Ps[2][2048];   // double-buffered P (32x64)
    __shared__ float lsum[32];

    *(float4*)&f1s[tid << 2] = *(const float4*)&f1g[(b << 11) + (tid << 2)];

    // ---- phase-A mapping: thread -> (row pi, j-quad pj4) ----
    const int pi  = tid >> 4;
    const int pj4 = tid & 15;
    const float fm  = f1maxg[b];
    const float f2v = f2g[(b << 11) + i0 + pi];
    const float Mshift = fmaxf(f2v + fm, LRELU_ALPHA * (f2v + fm)) - 1000.0f;
    const int pwo = (pi << 6) + ((((pj4 << 3)) ^ ((pi & 7) << 4)) >> 1);

    // per-thread 128-bit adj mask: covers ALL 32 iterations
    const uint4 aw = *(const uint4*)(tb + ((((size_t)(b << 11) + i0 + pi) << 4) + pj4) * 4);

    // ---- phase-B mapping: wave w -> d-slice [w*16, w*16+16), rows 0..31 ----
    const int w    = tid >> 6;
    const int lane = tid & 63;
    const int il   = lane & 15;
    const int kg   = lane >> 4;
    const int aof0 = (il << 6) + (((kg << 4) ^ ((il & 7) << 4)) >> 1);
    const int aof1 = (il << 6) + (((64 | (kg << 4)) ^ ((il & 7) << 4)) >> 1);
    const __bf16* pB = pack + ((size_t)b << 18) + (w << 10) + (lane << 3);

    f32x4 acc0 = {0.f,0.f,0.f,0.f}, acc1 = {0.f,0.f,0.f,0.f};
    float den = 0.f;

    // ---- prologue ----
    bf16x8 Bc0 = *(const bf16x8*)(pB);            // B tile 0, k-half 0
    bf16x8 Bc1 = *(const bf16x8*)(pB + 512);      // k-half 1

    wg_barrier();                                 // f1s ready

    PCOMPUTE(0, 0);                               // P(0) -> Ps[0]

    wg_barrier();                                 // Ps[0] ready

    for (int t = 0; t < 31; ++t) {
        const __bf16* pBn = pB + ((size_t)(t + 1) << 13);
        bf16x8 Bn0 = *(const bf16x8*)(pBn);
        bf16x8 Bn1 = *(const bf16x8*)(pBn + 512);

        bf16x8 A00 = *(const bf16x8*)(&Ps[t & 1][aof0]);          // rows 0-15
        bf16x8 A01 = *(const bf16x8*)(&Ps[t & 1][aof1]);
        bf16x8 A10 = *(const bf16x8*)(&Ps[t & 1][aof0 + 1024]);   // rows 16-31
        bf16x8 A11 = *(const bf16x8*)(&Ps[t & 1][aof1 + 1024]);

        PCOMPUTE(t + 1, (t + 1) & 1);

        acc0 = __builtin_amdgcn_mfma_f32_16x16x32_bf16(A00, Bc0, acc0, 0, 0, 0);
        acc0 = __builtin_amdgcn_mfma_f32_16x16x32_bf16(A01, Bc1, acc0, 0, 0, 0);
        acc1 = __builtin_amdgcn_mfma_f32_16x16x32_bf16(A10, Bc0, acc1, 0, 0, 0);
        acc1 = __builtin_amdgcn_mfma_f32_16x16x32_bf16(A11, Bc1, acc1, 0, 0, 0);

        Bc0 = Bn0; Bc1 = Bn1;

        wg_barrier();                             // Ps[(t+1)&1] ready / reads done
    }

    {   // peeled t = 31
        bf16x8 A00 = *(const bf16x8*)(&Ps[1][aof0]);
        bf16x8 A01 = *(const bf16x8*)(&Ps[1][aof1]);
        bf16x8 A10 = *(const bf16x8*)(&Ps[1][aof0 + 1024]);
        bf16x8 A11 = *(const bf16x8*)(&Ps[1][aof1 + 1024]);
        acc0 = __builtin_amdgcn_mfma_f32_16x16x32_bf16(A00, Bc0, acc0, 0, 0, 0);
        acc0 = __builtin_amdgcn_mfma_f32_16x16x32_bf16(A01, Bc1, acc0, 0, 0, 0);
        acc1 = __builtin_amdgcn_mfma_f32_16x16x32_bf16(A10, Bc0, acc1, 0, 0, 0);
        acc1 = __builtin_amdgcn_mfma_f32_16x16x32_bf16(A11, Bc1, acc1, 0, 0, 0);
    }

    // ---- denominator: reduce over the 16 j-quad lanes of each row ----
    den += __shfl_xor(den, 1);
    den += __shfl_xor(den, 2);
    den += __shfl_xor(den, 4);
    den += __shfl_xor(den, 8);
    if (pj4 == 0) lsum[pi] = den;
    wg_barrier();

    // ---- epilogue: normalize, elu, residual (bf16 h) ----
    #pragma unroll
    for (int r = 0; r < 4; ++r) {
        const int row0 = (kg << 2) + r;           // acc0 rows 0-15
        const int row1 = row0 + 16;               // acc1 rows 16-31
        const float dn0 = lsum[row0];
        const float dn1 = lsum[row1];
        const size_t g0 = (((size_t)(b << 11) + i0 + row0) << 7) + (w << 4) + il;
        const size_t g1 = (((size_t)(b << 11) + i0 + row1) << 7) + (w << 4) + il;
        float v, e;
        v = acc0[r] / dn0; e = (v > 0.f) ? v : (__expf(v) - 1.f);
        out[g0] = e + (float)hb[g0];
        v = acc1[r] / dn1; e = (v > 0.f) ? v : (__expf(v) - 1.f);
        out[g1] = e + (float)hb[g1];
    }
}

// ---------------------------------------------------------------------------
extern "C" void kernel_launch(void* const* d_in, const int* in_sizes, int n_in,
                              void* d_out, int out_size, void* d_ws, size_t ws_size,
                              hipStream_t stream)
{
    const float* inp = (const float*)d_in[0];
    const int*   adj = (const int*)d_in[1];
    const float* W   = (const float*)d_in[2];
    const float* a   = (const float*)d_in[3];
    float* out = (float*)d_out;

    // workspace layout (~12.2 MB)
    char* ws = (char*)d_ws;
    __bf16*       hb    = (__bf16*)ws;                       // 4 MB
    __bf16*       pack  = (__bf16*)(ws + (4 << 20));         // 4 MB
    unsigned int* tb    = (unsigned int*)(ws + (8 << 20));   // 4 MB
    float*        f1    = (float*)(ws + (12 << 20));         // 64 KB
    float*        f2    = (float*)(ws + (12 << 20) + 65536);
    float*        f1max = (float*)(ws + (12 << 20) + 131072);

    gat_adjpack<<<1024, 256, 0, stream>>>(adj, tb);
    gat_prep<<<2048, 128, 0, stream>>>(inp, W, a, hb, f1, f2);
    gat_f1max<<<8, 256, 0, stream>>>(f1, f1max);
    gat_pack<<<512, 256, 0, stream>>>(hb, pack);
    gat_attn6<<<512, 512, 0, stream>>>(tb, hb, pack, f1, f2, f1max, out);
}

// Round 7
// 75.399 us; speedup vs baseline: 1.0401x; 1.0401x over previous
//
#include <hip/hip_runtime.h>
#include <hip/hip_bf16.h>

typedef __bf16 bf16x8 __attribute__((ext_vector_type(8)));
typedef __bf16 bf16x4 __attribute__((ext_vector_type(4)));
typedef float  f32x4  __attribute__((ext_vector_type(4)));

#define LRELU_ALPHA 0.2f
#define LOG2E 1.44269504088896340736f

// native 2^x (single v_exp_f32, no OCML call)
__device__ __forceinline__ float fexp2(float x) {
#if __has_builtin(__builtin_amdgcn_exp2f)
    return __builtin_amdgcn_exp2f(x);
#else
    float r; asm("v_exp_f32 %0, %1" : "=v"(r) : "v"(x)); return r;
#endif
}

// raw barrier: drains LDS (lgkmcnt) but leaves global prefetches (vmcnt) in flight
__device__ __forceinline__ void wg_barrier() {
    asm volatile("s_waitcnt lgkmcnt(0)" ::: "memory");
    __builtin_amdgcn_s_barrier();
    asm volatile("" ::: "memory");
}

// ---------------------------------------------------------------------------
// Kernel 1: h = inp @ W (8 rows/block) -> hb (bf16), f1 = log2e*(h·a1),
// f2 = log2e*(h·a2). h kept ONLY as bf16 (residual tolerance allows it).
// ---------------------------------------------------------------------------
__global__ __launch_bounds__(128) void gat_prep(
    const float* __restrict__ inp, const float* __restrict__ W,
    const float* __restrict__ a,
    __bf16* __restrict__ hb, float* __restrict__ f1, float* __restrict__ f2)
{
    const int r0 = blockIdx.x << 3;
    const int d  = threadIdx.x;
    __shared__ float sIn[8][128];
    __shared__ float sRed[8][4];
    #pragma unroll
    for (int r = 0; r < 8; ++r)
        sIn[r][d] = inp[(size_t)(r0 + r) * 128 + d];
    __syncthreads();

    float acc[8] = {0.f,0.f,0.f,0.f,0.f,0.f,0.f,0.f};
    #pragma unroll 4
    for (int k = 0; k < 128; ++k) {
        float wv = W[k * 128 + d];
        #pragma unroll
        for (int r = 0; r < 8; ++r) acc[r] += sIn[r][k] * wv;
    }

    const float a1 = a[d], a2 = a[128 + d];
    const int wv = d >> 6;
    #pragma unroll
    for (int r = 0; r < 8; ++r) {
        hb[(size_t)(r0 + r) * 128 + d] = (__bf16)acc[r];
        float t1 = acc[r] * a1;
        float t2 = acc[r] * a2;
        #pragma unroll
        for (int m = 1; m < 64; m <<= 1) {
            t1 += __shfl_xor(t1, m);
            t2 += __shfl_xor(t2, m);
        }
        if ((d & 63) == 0) { sRed[r][wv] = t1; sRed[r][2 + wv] = t2; }
    }
    __syncthreads();
    if (d < 8) {
        f1[r0 + d] = (sRed[d][0] + sRed[d][1]) * LOG2E;
        f2[r0 + d] = (sRed[d][2] + sRed[d][3]) * LOG2E;
    }
}

// ---------------------------------------------------------------------------
// Kernel 2: per-batch max of (prescaled) f1
// ---------------------------------------------------------------------------
__global__ __launch_bounds__(256) void gat_f1max(
    const float* __restrict__ f1, float* __restrict__ f1max)
{
    const int b = blockIdx.x;
    const int t = threadIdx.x;
    float m = -1e30f;
    for (int j = t; j < 2048; j += 256) m = fmaxf(m, f1[b * 2048 + j]);
    #pragma unroll
    for (int k = 1; k < 64; k <<= 1) m = fmaxf(m, __shfl_xor(m, k));
    __shared__ float sm[4];
    if ((t & 63) == 0) sm[t >> 6] = m;
    __syncthreads();
    if (t == 0) f1max[b] = fmaxf(fmaxf(sm[0], sm[1]), fmaxf(sm[2], sm[3]));
}

// ---------------------------------------------------------------------------
// Kernel 3: hb (bf16 [b][n][128]) -> pack: fragment-major bf16 B-operands.
// pack element offset = (b*32 + jt)*8192 + frag*512 + lane*8, frag = D*2+jh.
// Fragment lane(il,kg) elem e = h[jt*64 + jh*32 + kg*8 + e][D*16 + il].
// ---------------------------------------------------------------------------
__global__ __launch_bounds__(256) void gat_pack(
    const __bf16* __restrict__ hb, __bf16* __restrict__ pack)
{
    __shared__ __bf16 tile[64][72];
    const int tid = threadIdx.x;
    const int bidx = blockIdx.x;         // 512 blocks
    const int b  = bidx >> 6;
    const int tI = bidx & 63;
    const int n0 = (tI >> 1) << 6;       // j-range 64
    const int d0 = (tI & 1) << 6;        // d-range 64
    #pragma unroll
    for (int pass = 0; pass < 2; ++pass) {
        int row = (tid >> 3) + (pass << 5);     // j within tile
        int c   = (tid & 7) << 3;               // d within tile
        *(bf16x8*)&tile[row][c] =
            *(const bf16x8*)(hb + (size_t)(b * 2048 + n0 + row) * 128 + d0 + c);
    }
    __syncthreads();
    const int lane = tid & 63;
    const int il = lane & 15;
    const int kg = lane >> 4;
    #pragma unroll
    for (int pass = 0; pass < 2; ++pass) {
        const int f  = (tid >> 6) + (pass << 2);   // fragment 0..7 of this block
        const int Dl = f >> 1;
        const int jh = f & 1;
        union { __bf16 e[8]; bf16x8 v; } u;
        #pragma unroll
        for (int e = 0; e < 8; ++e)
            u.e[e] = tile[(jh << 5) + (kg << 3) + e][(Dl << 4) + il];
        const size_t off = (((size_t)(b << 5) + (n0 >> 6)) << 13)
                         + ((size_t)((((d0 >> 4) + Dl) << 1) | jh) << 9)
                         + (lane << 3);
        *(bf16x8*)(pack + off) = u.v;
    }
}

// ---------------------------------------------------------------------------
// Kernel 3b: adj (int32, 128 MB) -> tb bitmask (4 MB), consumer-major:
// tb[row][pj4] = int4 (128 bits); bit (t*4+e) = adj[row][t*64 + pj4*4 + e].
// Pure streaming read (coalesced int4 + ballot) -> runs at ~fill rate.
// ---------------------------------------------------------------------------
__global__ __launch_bounds__(256) void gat_adjpack(
    const int* __restrict__ adj, unsigned int* __restrict__ tb)
{
    __shared__ unsigned long long blt[16][8][4];
    const int tid  = threadIdx.x;
    const int w    = tid >> 6;
    const int lane = tid & 63;
    const int base = blockIdx.x << 4;          // 1024 blocks * 16 rows

    // phase 1: each wave packs 4 rows via ballots
    #pragma unroll
    for (int rr = 0; rr < 4; ++rr) {
        const int rloc = (w << 2) + rr;
        const int* ap = adj + ((size_t)(base + rloc) << 11) + (lane << 2);
        unsigned long long kept = 0ull;
        #pragma unroll
        for (int s = 0; s < 8; ++s) {
            int4 v = *(const int4*)(ap + (s << 8));
            unsigned long long b0 = __ballot(v.x > 0);
            unsigned long long b1 = __ballot(v.y > 0);
            unsigned long long b2 = __ballot(v.z > 0);
            unsigned long long b3 = __ballot(v.w > 0);
            const int e4 = lane & 3;
            unsigned long long be = (e4 == 0) ? b0 : (e4 == 1) ? b1
                                  : (e4 == 2) ? b2 : b3;
            kept = ((lane >> 2) == s) ? be : kept;
        }
        if (lane < 32) blt[rloc][lane >> 2][lane & 3] = kept;
    }
    __syncthreads();

    // phase 2: thread (r, pj4) assembles its consumer int4
    const int r   = tid >> 4;
    const int pj4 = tid & 15;
    unsigned int w0 = 0, w1 = 0, w2 = 0, w3 = 0;
    #pragma unroll
    for (int s = 0; s < 8; ++s) {
        unsigned long long q0 = blt[r][s][0];
        unsigned long long q1 = blt[r][s][1];
        unsigned long long q2 = blt[r][s][2];
        unsigned long long q3 = blt[r][s][3];
        #pragma unroll
        for (int tt = 0; tt < 4; ++tt) {
            const int t = (s << 2) + tt;
            const int L = (tt << 4) + pj4;
            unsigned int nib = (unsigned int)((q0 >> L) & 1)
                             | ((unsigned int)((q1 >> L) & 1) << 1)
                             | ((unsigned int)((q2 >> L) & 1) << 2)
                             | ((unsigned int)((q3 >> L) & 1) << 3);
            const unsigned int sh = (unsigned int)((t & 7) << 2);
            if (t < 8)       w0 |= nib << sh;
            else if (t < 16) w1 |= nib << sh;
            else if (t < 24) w2 |= nib << sh;
            else             w3 |= nib << sh;
        }
    }
    uint4 o; o.x = w0; o.y = w1; o.z = w2; o.w = w3;
    *(uint4*)(tb + (((size_t)(base + r) << 4) + pj4) * 4) = o;
}

// ---------------------------------------------------------------------------
// Kernel 4 v7: identical structure to v6; P-compute slimmed to native
// v_exp_f32 + hoisted constants + cndmask masking.
// ---------------------------------------------------------------------------
#define PCOMPUTE(TT, BUF) do {                                                \
    float4 fv = *(const float4*)&f1s[((TT) << 6) + (pj4 << 2)];               \
    const unsigned int wvm = ((TT) & 16) ? (((TT) & 8) ? aw.w : aw.z)         \
                                         : (((TT) & 8) ? aw.y : aw.x);        \
    const unsigned int nib = (wvm >> (((TT) & 7) << 2)) & 0xFu;               \
    float p0, p1, p2, p3;                                                     \
    { float x1 = fv.x + C1, x2 = __builtin_fmaf(LRELU_ALPHA, fv.x, C2);       \
      p0 = fexp2(fmaxf(x1, x2)); p0 = (nib & 1u) ? p0 : 0.f; }                \
    { float x1 = fv.y + C1, x2 = __builtin_fmaf(LRELU_ALPHA, fv.y, C2);       \
      p1 = fexp2(fmaxf(x1, x2)); p1 = (nib & 2u) ? p1 : 0.f; }                \
    { float x1 = fv.z + C1, x2 = __builtin_fmaf(LRELU_ALPHA, fv.z, C2);       \
      p2 = fexp2(fmaxf(x1, x2)); p2 = (nib & 4u) ? p2 : 0.f; }                \
    { float x1 = fv.w + C1, x2 = __builtin_fmaf(LRELU_ALPHA, fv.w, C2);       \
      p3 = fexp2(fmaxf(x1, x2)); p3 = (nib & 8u) ? p3 : 0.f; }                \
    bf16x4 pb;                                                                \
    pb[0] = (__bf16)p0; pb[1] = (__bf16)p1;                                   \
    pb[2] = (__bf16)p2; pb[3] = (__bf16)p3;                                   \
    den += (float)pb[0] + (float)pb[1] + (float)pb[2] + (float)pb[3];         \
    *(bf16x4*)(&Ps[BUF][pwo]) = pb;                                           \
} while (0)

__global__ __launch_bounds__(512, 4) void gat_attn7(
    const unsigned int* __restrict__ tb, const __bf16* __restrict__ hb,
    const __bf16* __restrict__ pack, const float* __restrict__ f1g,
    const float* __restrict__ f2g, const float* __restrict__ f1maxg,
    float* __restrict__ out)
{
    const int bid = ((blockIdx.x & 7) << 6) | (blockIdx.x >> 3);  // batch<->XCD
    const int b  = bid >> 6;
    const int i0 = (bid & 63) << 5;
    const int tid = threadIdx.x;

    __shared__ float f1s[2048];
    __shared__ alignas(16) __bf16 Ps[2][2048];   // double-buffered P (32x64)
    __shared__ float lsum[32];

    *(float4*)&f1s[tid << 2] = *(const float4*)&f1g[(b << 11) + (tid << 2)];

    // ---- phase-A mapping: thread -> (row pi, j-quad pj4) ----
    const int pi  = tid >> 4;
    const int pj4 = tid & 15;
    const float fm  = f1maxg[b];
    const float f2v = f2g[(b << 11) + i0 + pi];
    const float M   = fmaxf(f2v + fm, LRELU_ALPHA * (f2v + fm));  // exact bound
    const float C1  = f2v - M;                                    // e = max(fv+C1, .2fv+C2) <= 0
    const float C2  = __builtin_fmaf(LRELU_ALPHA, f2v, -M);
    const int pwo = (pi << 6) + ((((pj4 << 3)) ^ ((pi & 7) << 4)) >> 1);

    // per-thread 128-bit adj mask: covers ALL 32 iterations
    const uint4 aw = *(const uint4*)(tb + ((((size_t)(b << 11) + i0 + pi) << 4) + pj4) * 4);

    // ---- phase-B mapping: wave w -> d-slice [w*16, w*16+16), rows 0..31 ----
    const int w    = tid >> 6;
    const int lane = tid & 63;
    const int il   = lane & 15;
    const int kg   = lane >> 4;
    const int aof0 = (il << 6) + (((kg << 4) ^ ((il & 7) << 4)) >> 1);
    const int aof1 = (il << 6) + (((64 | (kg << 4)) ^ ((il & 7) << 4)) >> 1);
    const __bf16* pB = pack + ((size_t)b << 18) + (w << 10) + (lane << 3);

    f32x4 acc0 = {0.f,0.f,0.f,0.f}, acc1 = {0.f,0.f,0.f,0.f};
    float den = 0.f;

    // ---- prologue ----
    bf16x8 Bc0 = *(const bf16x8*)(pB);            // B tile 0, k-half 0
    bf16x8 Bc1 = *(const bf16x8*)(pB + 512);      // k-half 1

    wg_barrier();                                 // f1s ready

    PCOMPUTE(0, 0);                               // P(0) -> Ps[0]

    wg_barrier();                                 // Ps[0] ready

    for (int t = 0; t < 31; ++t) {
        const __bf16* pBn = pB + ((size_t)(t + 1) << 13);
        bf16x8 Bn0 = *(const bf16x8*)(pBn);
        bf16x8 Bn1 = *(const bf16x8*)(pBn + 512);

        bf16x8 A00 = *(const bf16x8*)(&Ps[t & 1][aof0]);          // rows 0-15
        bf16x8 A01 = *(const bf16x8*)(&Ps[t & 1][aof1]);
        bf16x8 A10 = *(const bf16x8*)(&Ps[t & 1][aof0 + 1024]);   // rows 16-31
        bf16x8 A11 = *(const bf16x8*)(&Ps[t & 1][aof1 + 1024]);

        PCOMPUTE(t + 1, (t + 1) & 1);

        acc0 = __builtin_amdgcn_mfma_f32_16x16x32_bf16(A00, Bc0, acc0, 0, 0, 0);
        acc0 = __builtin_amdgcn_mfma_f32_16x16x32_bf16(A01, Bc1, acc0, 0, 0, 0);
        acc1 = __builtin_amdgcn_mfma_f32_16x16x32_bf16(A10, Bc0, acc1, 0, 0, 0);
        acc1 = __builtin_amdgcn_mfma_f32_16x16x32_bf16(A11, Bc1, acc1, 0, 0, 0);

        Bc0 = Bn0; Bc1 = Bn1;

        wg_barrier();                             // Ps[(t+1)&1] ready / reads done
    }

    {   // peeled t = 31
        bf16x8 A00 = *(const bf16x8*)(&Ps[1][aof0]);
        bf16x8 A01 = *(const bf16x8*)(&Ps[1][aof1]);
        bf16x8 A10 = *(const bf16x8*)(&Ps[1][aof0 + 1024]);
        bf16x8 A11 = *(const bf16x8*)(&Ps[1][aof1 + 1024]);
        acc0 = __builtin_amdgcn_mfma_f32_16x16x32_bf16(A00, Bc0, acc0, 0, 0, 0);
        acc0 = __builtin_amdgcn_mfma_f32_16x16x32_bf16(A01, Bc1, acc0, 0, 0, 0);
        acc1 = __builtin_amdgcn_mfma_f32_16x16x32_bf16(A10, Bc0, acc1, 0, 0, 0);
        acc1 = __builtin_amdgcn_mfma_f32_16x16x32_bf16(A11, Bc1, acc1, 0, 0, 0);
    }

    // ---- denominator: reduce over the 16 j-quad lanes of each row ----
    den += __shfl_xor(den, 1);
    den += __shfl_xor(den, 2);
    den += __shfl_xor(den, 4);
    den += __shfl_xor(den, 8);
    if (pj4 == 0) lsum[pi] = den;
    wg_barrier();

    // ---- epilogue: normalize, elu, residual (bf16 h) ----
    #pragma unroll
    for (int r = 0; r < 4; ++r) {
        const int row0 = (kg << 2) + r;           // acc0 rows 0-15
        const int row1 = row0 + 16;               // acc1 rows 16-31
        const float dn0 = lsum[row0];
        const float dn1 = lsum[row1];
        const size_t g0 = (((size_t)(b << 11) + i0 + row0) << 7) + (w << 4) + il;
        const size_t g1 = (((size_t)(b << 11) + i0 + row1) << 7) + (w << 4) + il;
        float v, e;
        v = acc0[r] / dn0; e = (v > 0.f) ? v : (__expf(v) - 1.f);
        out[g0] = e + (float)hb[g0];
        v = acc1[r] / dn1; e = (v > 0.f) ? v : (__expf(v) - 1.f);
        out[g1] = e + (float)hb[g1];
    }
}

// ---------------------------------------------------------------------------
extern "C" void kernel_launch(void* const* d_in, const int* in_sizes, int n_in,
                              void* d_out, int out_size, void* d_ws, size_t ws_size,
                              hipStream_t stream)
{
    const float* inp = (const float*)d_in[0];
    const int*   adj = (const int*)d_in[1];
    const float* W   = (const float*)d_in[2];
    const float* a   = (const float*)d_in[3];
    float* out = (float*)d_out;

    // workspace layout (~12.2 MB)
    char* ws = (char*)d_ws;
    __bf16*       hb    = (__bf16*)ws;                       // 4 MB
    __bf16*       pack  = (__bf16*)(ws + (4 << 20));         // 4 MB
    unsigned int* tb    = (unsigned int*)(ws + (8 << 20));   // 4 MB
    float*        f1    = (float*)(ws + (12 << 20));         // 64 KB
    float*        f2    = (float*)(ws + (12 << 20) + 65536);
    float*        f1max = (float*)(ws + (12 << 20) + 131072);

    gat_adjpack<<<1024, 256, 0, stream>>>(adj, tb);
    gat_prep<<<2048, 128, 0, stream>>>(inp, W, a, hb, f1, f2);
    gat_f1max<<<8, 256, 0, stream>>>(f1, f1max);
    gat_pack<<<512, 256, 0, stream>>>(hb, pack);
    gat_attn7<<<512, 512, 0, stream>>>(tb, hb, pack, f1, f2, f1max, out);
}